// Round 3
// baseline (987.253 us; speedup 1.0000x reference)
//
#include <hip/hip_runtime.h>

#define N_NODES 10000
#define EMB 10
#define NCHUNK 2500           // N_NODES/4 float4 chunks per row
#define ROWS 4                // rows per group
#define GROUPS 5              // row-groups per block
#define NBLK 500              // persistent grid (<= 2 blocks/CU * 256 CUs)
#define EDGE_BLKS 256         // edge phase uses same geometry as old k_edge_sum

typedef float f32x4 __attribute__((ext_vector_type(4)));

// workspace float offsets (first 64 floats memset to 0 each launch)
#define WS_SSUM 16            // 10 floats
#define WS_BAR  32            // 3 ints
#define WS_PART 64            // EDGE_BLKS*EMB floats of edge partials
#define WS_EMBT 4096          // 10*10000 floats (transposed emb from pass 1)

struct Params {
    const float* A; const float* f; const float* w; int E;
    const float* ws_w; const float* ws_b;
    const float* wnp_w; const float* wnp_b;
    const float* wnw_w; const float* wnw_b;
    const float* wew_w; const float* wew_b;
    const float* wqr_w; const float* wqr_b;
    const float* wqa_w; const float* wqa_b;
    const float* wqact_w; const float* wqact_b;
    float* part; float* embT; float* ssum; int* bar;
    float* q_out; float* emb_out;
};

// All 500 blocks are resident (guaranteed by __launch_bounds__(256,2) ->
// >=2 blocks/CU), so a counting barrier cannot deadlock. __threadfence()
// provides device-scope release/acquire (L2 writeback+invalidate) around it,
// which is required because per-XCD L2s are not coherent.
__device__ __forceinline__ void grid_barrier(int* bar) {
    __threadfence();
    __syncthreads();
    if (threadIdx.x == 0) {
        atomicAdd(bar, 1);
        while (atomicAdd(bar, 0) < NBLK) __builtin_amdgcn_s_sleep(16);
    }
    __syncthreads();
    __threadfence();
}

__global__ __launch_bounds__(256, 2) void k_main(Params p) {
    const int tid  = threadIdx.x;
    const int wave = tid >> 6;
    const int lane = tid & 63;
    const int b    = blockIdx.x;

    const float* __restrict__ A     = p.A;
    const float* __restrict__ f     = p.f;
    float* __restrict__ embT        = p.embT;
    float* __restrict__ emb_out     = p.emb_out;
    float* __restrict__ q_out       = p.q_out;

    __shared__ float red[4][EMB];
    __shared__ float s_sEdge[EMB];
    __shared__ float s_cb2[EMB];
    __shared__ float s_qvec[EMB];
    __shared__ float part_l[4][ROWS * EMB];
    __shared__ float colp[ROWS * EMB];
    __shared__ float s_colsum[EMB];
    __shared__ float s_q[GROUPS * ROWS];

    // ---------------- phase E: edge partial sums (blocks 0..255) ----------------
    if (b < EDGE_BLKS) {
        float aw[EMB], ab[EMB], acc[EMB];
#pragma unroll
        for (int j = 0; j < EMB; ++j) { aw[j] = p.wew_w[j]; ab[j] = p.wew_b[j]; acc[j] = 0.f; }
        for (int e = b * 256 + tid; e < p.E; e += EDGE_BLKS * 256) {
            float we = p.w[e];
#pragma unroll
            for (int j = 0; j < EMB; ++j) acc[j] += fmaxf(we * aw[j] + ab[j], 0.f);
        }
#pragma unroll
        for (int m = 1; m < 64; m <<= 1)
#pragma unroll
            for (int j = 0; j < EMB; ++j) acc[j] += __shfl_xor(acc[j], m, 64);
        if (lane == 0)
#pragma unroll
            for (int j = 0; j < EMB; ++j) red[wave][j] = acc[j];
        __syncthreads();
        if (tid < EMB)
            p.part[b * EMB + tid] =
                red[0][tid] + red[1][tid] + red[2][tid] + red[3][tid];
    }
    grid_barrier(p.bar + 0);

    // ------------- reduce 256 partials -> sEdge -> cb2, qvec (every block) -------------
    {
        float acc[EMB];
#pragma unroll
        for (int j = 0; j < EMB; ++j) acc[j] = p.part[tid * EMB + j];  // one partial/thread
#pragma unroll
        for (int m = 1; m < 64; m <<= 1)
#pragma unroll
            for (int j = 0; j < EMB; ++j) acc[j] += __shfl_xor(acc[j], m, 64);
        __syncthreads();               // edge-phase red[] readers done
        if (lane == 0)
#pragma unroll
            for (int j = 0; j < EMB; ++j) red[wave][j] = acc[j];
        __syncthreads();
        if (tid < EMB)
            s_sEdge[tid] = red[0][tid] + red[1][tid] + red[2][tid] + red[3][tid];
        __syncthreads();
        if (tid < EMB) {
            int j = tid;
            float v = p.wnw_b[j];
#pragma unroll
            for (int k = 0; k < EMB; ++k) v += s_sEdge[k] * p.wnw_w[k * EMB + j];
            s_cb2[j] = v + p.ws_b[j] + p.wnp_b[j];
            float qv = 0.f;
#pragma unroll
            for (int k = 0; k < EMB; ++k) qv += p.wqact_w[j * EMB + k] * p.wqr_w[EMB + k];
            s_qvec[j] = qv;
        }
        __syncthreads();
    }
    float cb2[EMB], wsw[EMB];
#pragma unroll
    for (int j = 0; j < EMB; ++j) { cb2[j] = s_cb2[j]; wsw[j] = p.ws_w[j]; }

    // ---------------- pass 1: emb2 (iters 1+2 fused, e on the fly) ----------------
#pragma unroll 1
    for (int g = 0; g < GROUPS; ++g) {
        const int r0 = (b * GROUPS + g) * ROWS;
        float acc[ROWS][EMB] = {};
        const f32x4* A0 = (const f32x4*)(A + (size_t)(r0 + 0) * N_NODES);
        const f32x4* A1 = (const f32x4*)(A + (size_t)(r0 + 1) * N_NODES);
        const f32x4* A2 = (const f32x4*)(A + (size_t)(r0 + 2) * N_NODES);
        const f32x4* A3 = (const f32x4*)(A + (size_t)(r0 + 3) * N_NODES);
        const f32x4* F4 = (const f32x4*)f;

#define BODY1(c)                                                                  \
    {                                                                             \
        f32x4 a0 = A0[c], a1 = A1[c], a2 = A2[c], a3 = A3[c];                     \
        f32x4 f4 = F4[c];                                                         \
        _Pragma("unroll")                                                         \
        for (int j = 0; j < EMB; ++j) {                                           \
            f32x4 e;                                                              \
            e.x = fmaxf(f4.x * wsw[j] + cb2[j], 0.f);                             \
            e.y = fmaxf(f4.y * wsw[j] + cb2[j], 0.f);                             \
            e.z = fmaxf(f4.z * wsw[j] + cb2[j], 0.f);                             \
            e.w = fmaxf(f4.w * wsw[j] + cb2[j], 0.f);                             \
            acc[0][j] += a0.x * e.x + a0.y * e.y + a0.z * e.z + a0.w * e.w;       \
            acc[1][j] += a1.x * e.x + a1.y * e.y + a1.z * e.z + a1.w * e.w;       \
            acc[2][j] += a2.x * e.x + a2.y * e.y + a2.z * e.z + a2.w * e.w;       \
            acc[3][j] += a3.x * e.x + a3.y * e.y + a3.z * e.z + a3.w * e.w;       \
        }                                                                         \
    }
#pragma unroll 1
        for (int s = 0; s < 9; ++s) { int c = s * 256 + tid; BODY1(c) }
        if (tid < NCHUNK - 9 * 256) { int c = 9 * 256 + tid; BODY1(c) }
#undef BODY1

#pragma unroll
        for (int m = 1; m < 64; m <<= 1)
#pragma unroll
            for (int r = 0; r < ROWS; ++r)
#pragma unroll
                for (int j = 0; j < EMB; ++j) acc[r][j] += __shfl_xor(acc[r][j], m, 64);

        __syncthreads();               // previous group's part_l readers done
        if (lane == 0)
#pragma unroll
            for (int r = 0; r < ROWS; ++r)
#pragma unroll
                for (int j = 0; j < EMB; ++j) part_l[wave][r * EMB + j] = acc[r][j];
        __syncthreads();

        if (tid < ROWS * EMB) {
            int r = tid / EMB, j = tid % EMB;
            float v = 0.f;
#pragma unroll
            for (int k = 0; k < EMB; ++k) {
                float yk = part_l[0][r * EMB + k] + part_l[1][r * EMB + k] +
                           part_l[2][r * EMB + k] + part_l[3][r * EMB + k];
                v += yk * p.wnp_w[k * EMB + j];
            }
            int i = r0 + r;
            v = fmaxf(f[i] * wsw[j] + cb2[j] + v, 0.f);
            embT[(size_t)j * N_NODES + i] = v;
        }
    }
    grid_barrier(p.bar + 1);           // embT now device-visible

    // ---------------- pass 2: emb3 + outputs ----------------
    if (tid < EMB) s_colsum[tid] = 0.f;
#pragma unroll 1
    for (int g = 0; g < GROUPS; ++g) {
        const int r0 = (b * GROUPS + g) * ROWS;
        float acc[ROWS][EMB] = {};
        const f32x4* A0 = (const f32x4*)(A + (size_t)(r0 + 0) * N_NODES);
        const f32x4* A1 = (const f32x4*)(A + (size_t)(r0 + 1) * N_NODES);
        const f32x4* A2 = (const f32x4*)(A + (size_t)(r0 + 2) * N_NODES);
        const f32x4* A3 = (const f32x4*)(A + (size_t)(r0 + 3) * N_NODES);

#define BODY2(c)                                                                  \
    {                                                                             \
        f32x4 a0 = A0[c], a1 = A1[c], a2 = A2[c], a3 = A3[c];                     \
        _Pragma("unroll")                                                         \
        for (int j = 0; j < EMB; ++j) {                                           \
            f32x4 e = ((const f32x4*)(embT + (size_t)j * N_NODES))[c];            \
            acc[0][j] += a0.x * e.x + a0.y * e.y + a0.z * e.z + a0.w * e.w;       \
            acc[1][j] += a1.x * e.x + a1.y * e.y + a1.z * e.z + a1.w * e.w;       \
            acc[2][j] += a2.x * e.x + a2.y * e.y + a2.z * e.z + a2.w * e.w;       \
            acc[3][j] += a3.x * e.x + a3.y * e.y + a3.z * e.z + a3.w * e.w;       \
        }                                                                         \
    }
        if (tid < NCHUNK - 9 * 256) { int c = 9 * 256 + tid; BODY2(c) }
#pragma unroll 1
        for (int s = 8; s >= 0; --s) { int c = s * 256 + tid; BODY2(c) }
#undef BODY2

#pragma unroll
        for (int m = 1; m < 64; m <<= 1)
#pragma unroll
            for (int r = 0; r < ROWS; ++r)
#pragma unroll
                for (int j = 0; j < EMB; ++j) acc[r][j] += __shfl_xor(acc[r][j], m, 64);

        __syncthreads();               // previous group's part_l/colp readers done
        if (lane == 0)
#pragma unroll
            for (int r = 0; r < ROWS; ++r)
#pragma unroll
                for (int j = 0; j < EMB; ++j) part_l[wave][r * EMB + j] = acc[r][j];
        __syncthreads();

        if (tid < ROWS * EMB) {
            int r = tid / EMB, j = tid % EMB;
            float v = 0.f;
#pragma unroll
            for (int k = 0; k < EMB; ++k) {
                float yk = part_l[0][r * EMB + k] + part_l[1][r * EMB + k] +
                           part_l[2][r * EMB + k] + part_l[3][r * EMB + k];
                v += yk * p.wnp_w[k * EMB + j];
            }
            int i = r0 + r;
            v = fmaxf(f[i] * wsw[j] + cb2[j] + v, 0.f);
            emb_out[(size_t)i * EMB + j] = v;    // final embeddings -> output
            colp[tid] = v;
        }
        __syncthreads();
        if (tid < EMB)
            s_colsum[tid] += colp[tid] + colp[EMB + tid] + colp[2 * EMB + tid] + colp[3 * EMB + tid];
        if (tid < ROWS) {
            float q = 0.f;
#pragma unroll
            for (int j = 0; j < EMB; ++j) q += colp[tid * EMB + j] * s_qvec[j];
            s_q[g * ROWS + tid] = q;
        }
    }
    if (tid < EMB) atomicAdd(&p.ssum[tid], s_colsum[tid]);
    grid_barrier(p.bar + 2);           // ssum complete

    // ---------------- epilogue: qc (redundant per thread) + final q writes ----------------
    if (tid < GROUPS * ROWS) {
        float ss[EMB];
#pragma unroll
        for (int k = 0; k < EMB; ++k) ss[k] = p.ssum[k];
        float qc = p.wqr_b[0];
#pragma unroll
        for (int t = 0; t < EMB; ++t) {
            float se = p.wqa_b[t];
#pragma unroll
            for (int k = 0; k < EMB; ++k) se += ss[k] * p.wqa_w[k * EMB + t];
            qc += se * p.wqr_w[t] + p.wqact_b[t] * p.wqr_w[EMB + t];
        }
        q_out[b * (GROUPS * ROWS) + tid] = s_q[tid] + qc;
    }
}

extern "C" void kernel_launch(void* const* d_in, const int* in_sizes, int n_in,
                              void* d_out, int out_size, void* d_ws, size_t ws_size,
                              hipStream_t stream) {
    (void)n_in; (void)out_size; (void)ws_size;
    float* ws  = (float*)d_ws;
    float* out = (float*)d_out;

    Params p;
    p.f       = (const float*)d_in[0];
    p.w       = (const float*)d_in[1];
    p.A       = (const float*)d_in[2];
    p.ws_w    = (const float*)d_in[3];
    p.ws_b    = (const float*)d_in[4];
    p.wnp_w   = (const float*)d_in[5];
    p.wnp_b   = (const float*)d_in[6];
    p.wnw_w   = (const float*)d_in[7];
    p.wnw_b   = (const float*)d_in[8];
    p.wew_w   = (const float*)d_in[9];
    p.wew_b   = (const float*)d_in[10];
    p.wqr_w   = (const float*)d_in[11];
    p.wqr_b   = (const float*)d_in[12];
    p.wqa_w   = (const float*)d_in[13];
    p.wqa_b   = (const float*)d_in[14];
    p.wqact_w = (const float*)d_in[15];
    p.wqact_b = (const float*)d_in[16];
    p.E       = in_sizes[1];
    p.part    = ws + WS_PART;
    p.embT    = ws + WS_EMBT;
    p.ssum    = ws + WS_SSUM;
    p.bar     = (int*)(ws + WS_BAR);
    p.q_out   = out;
    p.emb_out = out + N_NODES;

    hipMemsetAsync(ws, 0, 64 * sizeof(float), stream);   // zero ssum + barrier counters
    k_main<<<NBLK, 256, 0, stream>>>(p);
}

// Round 4
// 720.017 us; speedup vs baseline: 1.3712x; 1.3712x over previous
//
#include <hip/hip_runtime.h>

#define N_NODES 10000
#define EMB 10
#define NCHUNK 2500           // N_NODES/4 float4 chunks per row
#define ROWS 4                // rows per group
#define GROUPS 2              // row-groups per block
#define NBLK2 1250            // k_iter grid: 1250 blocks * 2 groups * 4 rows = 10000
                              // 1250 <= 5 blocks/CU * 256 CUs -> single scheduling
                              // round, no tail (2500-block grid ran ~1.6-2 rounds)

typedef float f32x4 __attribute__((ext_vector_type(4)));

// workspace float offsets (first 64 floats memset to 0 each launch)
#define WS_SEDGE 0
#define WS_SSUM  16
#define WS_EMBT  64           // 10 * 10000 floats (transposed emb, written by pass1)

// ---- K1: sum_e relu(w_e * wew_w[j] + wew_b[j]) -> sEdge[j] ----
__global__ void k_edge_sum(const float* __restrict__ w, int E,
                           const float* __restrict__ wew_w,
                           const float* __restrict__ wew_b,
                           float* __restrict__ sEdge) {
    __shared__ float red[4][EMB];
    float a[EMB], b[EMB], acc[EMB];
#pragma unroll
    for (int j = 0; j < EMB; ++j) { a[j] = wew_w[j]; b[j] = wew_b[j]; acc[j] = 0.f; }
    for (int e = blockIdx.x * blockDim.x + threadIdx.x; e < E; e += gridDim.x * blockDim.x) {
        float we = w[e];
#pragma unroll
        for (int j = 0; j < EMB; ++j) acc[j] += fmaxf(we * a[j] + b[j], 0.f);
    }
#pragma unroll
    for (int m = 1; m < 64; m <<= 1)
#pragma unroll
        for (int j = 0; j < EMB; ++j) acc[j] += __shfl_xor(acc[j], m, 64);
    int wave = threadIdx.x >> 6, lane = threadIdx.x & 63;
    if (lane == 0)
#pragma unroll
        for (int j = 0; j < EMB; ++j) red[wave][j] = acc[j];
    __syncthreads();
    if (threadIdx.x < EMB)
        atomicAdd(&sEdge[threadIdx.x],
                  red[0][threadIdx.x] + red[1][threadIdx.x] + red[2][threadIdx.x] + red[3][threadIdx.x]);
}

// ---- fused iteration kernel ----
// FIRST=true  (math iter 2): e computed on the fly from f (iter-1 closed form).
//                            Writes embT (transposed) only.
// FIRST=false (math iter 3): e loaded from embT. Writes emb row-major directly
//                            into the output buffer, per-row q partials, and
//                            one ssum atomic set per block (colsum fused).
// Each block handles GROUPS=2 row-groups: rows (b + g*NBLK2)*ROWS. All 1250
// blocks are co-resident (launch_bounds(256,5) -> 5 blocks/CU), so both passes
// run at full CU occupancy for their whole duration.
template <bool FIRST>
__global__ __launch_bounds__(256, 5) void k_iter(
    const float* __restrict__ A, const float* __restrict__ embT_in,
    const float* __restrict__ f, const float* __restrict__ ws_w,
    const float* __restrict__ ws_b, const float* __restrict__ wnp_w,
    const float* __restrict__ wnp_b, const float* __restrict__ wnw_w,
    const float* __restrict__ wnw_b, const float* __restrict__ sEdge,
    const float* __restrict__ wqr_w, const float* __restrict__ wqact_w,
    float* __restrict__ embT_out, float* __restrict__ emb_out,
    float* __restrict__ ssum, float* __restrict__ q_out) {
    const int tid  = threadIdx.x;
    const int wave = tid >> 6;
    const int lane = tid & 63;

    // per-block prologue: cb2[j] = ws_b + (sEdge@wnw_w + wnw_b) + wnp_b  (k_prep1 folded)
    __shared__ float s_cb2[EMB];
    __shared__ float s_qvec[EMB];
    __shared__ float part_l[4][ROWS * EMB];
    __shared__ float colp[ROWS * EMB];
    __shared__ float s_colsum[EMB];
    if (tid < EMB) {
        int j = tid;
        float v = wnw_b[j];
#pragma unroll
        for (int k = 0; k < EMB; ++k) v += sEdge[k] * wnw_w[k * EMB + j];
        s_cb2[j] = v + ws_b[j] + wnp_b[j];
        if (!FIRST) {   // qvec[t] = sum_k wqact_w[t][k] * wqr_w[EMB+k]  (weight-only)
            float qv = 0.f;
#pragma unroll
            for (int k = 0; k < EMB; ++k) qv += wqact_w[j * EMB + k] * wqr_w[EMB + k];
            s_qvec[j] = qv;
        }
        s_colsum[j] = 0.f;
    }
    __syncthreads();
    float cb2[EMB], wsw[EMB];
#pragma unroll
    for (int j = 0; j < EMB; ++j) { cb2[j] = s_cb2[j]; wsw[j] = ws_w[j]; }

#pragma unroll 1
    for (int g = 0; g < GROUPS; ++g) {
        const int r0 = (blockIdx.x + g * NBLK2) * ROWS;
        float acc[ROWS][EMB] = {};
        const f32x4* A0 = (const f32x4*)(A + (size_t)(r0 + 0) * N_NODES);
        const f32x4* A1 = (const f32x4*)(A + (size_t)(r0 + 1) * N_NODES);
        const f32x4* A2 = (const f32x4*)(A + (size_t)(r0 + 2) * N_NODES);
        const f32x4* A3 = (const f32x4*)(A + (size_t)(r0 + 3) * N_NODES);
        const f32x4* F4 = (const f32x4*)f;

#define BODY(c)                                                                     \
    {                                                                               \
        f32x4 a0 = A0[c], a1 = A1[c], a2 = A2[c], a3 = A3[c];                       \
        f32x4 f4;                                                                   \
        if (FIRST) f4 = F4[c];                                                      \
        _Pragma("unroll")                                                           \
        for (int j = 0; j < EMB; ++j) {                                             \
            f32x4 e;                                                                \
            if (FIRST) {                                                            \
                e.x = fmaxf(f4.x * wsw[j] + cb2[j], 0.f);                           \
                e.y = fmaxf(f4.y * wsw[j] + cb2[j], 0.f);                           \
                e.z = fmaxf(f4.z * wsw[j] + cb2[j], 0.f);                           \
                e.w = fmaxf(f4.w * wsw[j] + cb2[j], 0.f);                           \
            } else {                                                                \
                e = ((const f32x4*)(embT_in + (size_t)j * N_NODES))[c];             \
            }                                                                       \
            acc[0][j] += a0.x * e.x + a0.y * e.y + a0.z * e.z + a0.w * e.w;         \
            acc[1][j] += a1.x * e.x + a1.y * e.y + a1.z * e.z + a1.w * e.w;         \
            acc[2][j] += a2.x * e.x + a2.y * e.y + a2.z * e.z + a2.w * e.w;         \
            acc[3][j] += a3.x * e.x + a3.y * e.y + a3.z * e.z + a3.w * e.w;         \
        }                                                                           \
    }

        // 2500 chunks = 9 full 256-chunk steps + 196-chunk tail
#pragma unroll 1
        for (int s = 0; s < 9; ++s) { int c = s * 256 + tid; BODY(c) }
        if (tid < NCHUNK - 9 * 256) { int c = 9 * 256 + tid; BODY(c) }
#undef BODY

        // 64-lane butterfly: every lane ends with the wave's full partials
#pragma unroll
        for (int m = 1; m < 64; m <<= 1)
#pragma unroll
            for (int r = 0; r < ROWS; ++r)
#pragma unroll
                for (int j = 0; j < EMB; ++j) acc[r][j] += __shfl_xor(acc[r][j], m, 64);

        __syncthreads();               // previous group's part_l/colp readers done
        if (lane == 0)
#pragma unroll
            for (int r = 0; r < ROWS; ++r)
#pragma unroll
                for (int j = 0; j < EMB; ++j) part_l[wave][r * EMB + j] = acc[r][j];
        __syncthreads();

        if (tid < ROWS * EMB) {
            int r = tid / EMB, j = tid % EMB;
            float v = 0.f;
#pragma unroll
            for (int k = 0; k < EMB; ++k) {
                float yk = part_l[0][r * EMB + k] + part_l[1][r * EMB + k] +
                           part_l[2][r * EMB + k] + part_l[3][r * EMB + k];
                v += yk * wnp_w[k * EMB + j];
            }
            int i = r0 + r;
            v = fmaxf(f[i] * wsw[j] + cb2[j] + v, 0.f);
            if (FIRST) {
                embT_out[(size_t)j * N_NODES + i] = v;   // pass 2 only needs transposed
            } else {
                emb_out[(size_t)i * EMB + j] = v;        // final embeddings -> output
                colp[tid] = v;
            }
        }
        if (!FIRST) {
            __syncthreads();
            if (tid < EMB)             // accumulate colsum across both groups in LDS
                s_colsum[tid] += colp[tid] + colp[EMB + tid] +
                                 colp[2 * EMB + tid] + colp[3 * EMB + tid];
            if (tid < ROWS) {          // per-row q partial (scalar qc added later)
                float q = 0.f;
#pragma unroll
                for (int j = 0; j < EMB; ++j) q += colp[tid * EMB + j] * s_qvec[j];
                q_out[r0 + tid] = q;
            }
        }
    }
    if (!FIRST) {
        if (tid < EMB)                 // one ssum atomic set per block
            atomicAdd(&ssum[tid], s_colsum[tid]);
    }
}

// ---- K3: add the ssum-dependent scalar qc to all q values ----
__global__ void k_qc(const float* __restrict__ ssum,
                     const float* __restrict__ wqa_w, const float* __restrict__ wqa_b,
                     const float* __restrict__ wqr_w, const float* __restrict__ wqr_b,
                     const float* __restrict__ wqact_b,
                     float* __restrict__ q_out) {
    __shared__ float s_qc;
    if (threadIdx.x == 0) {
        float qc = wqr_b[0];
        for (int t = 0; t < EMB; ++t) {
            float se = wqa_b[t];
            for (int k = 0; k < EMB; ++k) se += ssum[k] * wqa_w[k * EMB + t];
            qc += se * wqr_w[t] + wqact_b[t] * wqr_w[EMB + t];
        }
        s_qc = qc;
    }
    __syncthreads();
    int i = blockIdx.x * blockDim.x + threadIdx.x;
    if (i < N_NODES) q_out[i] += s_qc;
}

extern "C" void kernel_launch(void* const* d_in, const int* in_sizes, int n_in,
                              void* d_out, int out_size, void* d_ws, size_t ws_size,
                              hipStream_t stream) {
    (void)n_in; (void)out_size; (void)ws_size;
    const float* f      = (const float*)d_in[0];
    const float* w      = (const float*)d_in[1];
    const float* A      = (const float*)d_in[2];
    const float* ws_w   = (const float*)d_in[3];
    const float* ws_b   = (const float*)d_in[4];
    const float* wnp_w  = (const float*)d_in[5];
    const float* wnp_b  = (const float*)d_in[6];
    const float* wnw_w  = (const float*)d_in[7];
    const float* wnw_b  = (const float*)d_in[8];
    const float* wew_w  = (const float*)d_in[9];
    const float* wew_b  = (const float*)d_in[10];
    const float* wqr_w  = (const float*)d_in[11];
    const float* wqr_b  = (const float*)d_in[12];
    const float* wqa_w  = (const float*)d_in[13];
    const float* wqa_b  = (const float*)d_in[14];
    const float* wqact_w = (const float*)d_in[15];
    const float* wqact_b = (const float*)d_in[16];
    float* ws  = (float*)d_ws;
    float* out = (float*)d_out;
    const int E = in_sizes[1];

    float* outEmb = out + N_NODES;   // embeddings written directly into output

    hipMemsetAsync(ws, 0, 64 * sizeof(float), stream);   // zero sEdge + ssum
    k_edge_sum<<<256, 256, 0, stream>>>(w, E, wew_w, wew_b, ws + WS_SEDGE);
    // pass 1 (math iters 1+2 fused): e on the fly from f
    k_iter<true><<<NBLK2, 256, 0, stream>>>(
        A, nullptr, f, ws_w, ws_b, wnp_w, wnp_b, wnw_w, wnw_b, ws + WS_SEDGE,
        nullptr, nullptr, ws + WS_EMBT, nullptr, nullptr, nullptr);
    // pass 2 (math iter 3): reads embT, writes emb/q partials/ssum
    k_iter<false><<<NBLK2, 256, 0, stream>>>(
        A, ws + WS_EMBT, f, ws_w, ws_b, wnp_w, wnp_b, wnw_w, wnw_b, ws + WS_SEDGE,
        wqr_w, wqact_w, nullptr, outEmb, ws + WS_SSUM, out);
    k_qc<<<(N_NODES + 255) / 256, 256, 0, stream>>>(ws + WS_SSUM, wqa_w, wqa_b,
                                                    wqr_w, wqr_b, wqact_b, out);
}

// Round 5
// 678.027 us; speedup vs baseline: 1.4561x; 1.0619x over previous
//
#include <hip/hip_runtime.h>

#define N_NODES 10000
#define EMB 10
#define NCHUNK 2500           // N_NODES/4 float4 chunks per row
#define ROWS 4                // rows per block

typedef float f32x4 __attribute__((ext_vector_type(4)));

// workspace float offsets
#define WS_SEDGE 0
#define WS_SSUM  16
#define WS_EMBT  64           // 10 * 10000 floats (transposed emb, written by pass1)

// ---- K1: sum_e relu(w_e * wew_w[j] + wew_b[j]) -> sEdge[j] ----
__global__ void k_edge_sum(const float* __restrict__ w, int E,
                           const float* __restrict__ wew_w,
                           const float* __restrict__ wew_b,
                           float* __restrict__ sEdge) {
    __shared__ float red[4][EMB];
    float a[EMB], b[EMB], acc[EMB];
#pragma unroll
    for (int j = 0; j < EMB; ++j) { a[j] = wew_w[j]; b[j] = wew_b[j]; acc[j] = 0.f; }
    for (int e = blockIdx.x * blockDim.x + threadIdx.x; e < E; e += gridDim.x * blockDim.x) {
        float we = w[e];
#pragma unroll
        for (int j = 0; j < EMB; ++j) acc[j] += fmaxf(we * a[j] + b[j], 0.f);
    }
#pragma unroll
    for (int m = 1; m < 64; m <<= 1)
#pragma unroll
        for (int j = 0; j < EMB; ++j) acc[j] += __shfl_xor(acc[j], m, 64);
    int wave = threadIdx.x >> 6, lane = threadIdx.x & 63;
    if (lane == 0)
#pragma unroll
        for (int j = 0; j < EMB; ++j) red[wave][j] = acc[j];
    __syncthreads();
    if (threadIdx.x < EMB)
        atomicAdd(&sEdge[threadIdx.x],
                  red[0][threadIdx.x] + red[1][threadIdx.x] + red[2][threadIdx.x] + red[3][threadIdx.x]);
}

// ---- fused iteration kernel ----
// FIRST=true  (math iter 2): e computed on the fly from f (iter-1 closed form),
//                            A loaded PLAIN. Writes embT only.
// FIRST=false (math iter 3): e loaded from embT; A loaded NONTEMPORAL. Writes emb
//                            row-major directly into the output buffer and
//                            atomically accumulates column sums (ssum).
template <bool FIRST>
__global__ __launch_bounds__(256) void k_iter(
    const float* __restrict__ A, const float* __restrict__ embT_in,
    const float* __restrict__ f, const float* __restrict__ ws_w,
    const float* __restrict__ ws_b, const float* __restrict__ wnp_w,
    const float* __restrict__ wnp_b, const float* __restrict__ wnw_w,
    const float* __restrict__ wnw_b, const float* __restrict__ sEdge,
    float* __restrict__ embT_out, float* __restrict__ emb_out,
    float* __restrict__ ssum) {
    const int tid  = threadIdx.x;
    const int wave = tid >> 6;
    const int lane = tid & 63;
    const int bid  = FIRST ? blockIdx.x : (gridDim.x - 1 - blockIdx.x);
    const int r0   = bid * ROWS;

    // per-block prologue: cb2[j] = ws_b + (sEdge@wnw_w + wnw_b) + wnp_b  (k_prep1 folded in)
    __shared__ float s_cb2[EMB];
    if (tid < EMB) {
        int j = tid;
        float v = wnw_b[j];
#pragma unroll
        for (int k = 0; k < EMB; ++k) v += sEdge[k] * wnw_w[k * EMB + j];
        s_cb2[j] = v + ws_b[j] + wnp_b[j];
    }
    __syncthreads();
    float cb2[EMB], wsw[EMB];
#pragma unroll
    for (int j = 0; j < EMB; ++j) { cb2[j] = s_cb2[j]; wsw[j] = ws_w[j]; }

    float acc[ROWS][EMB] = {};

    const f32x4* A0 = (const f32x4*)(A + (size_t)(r0 + 0) * N_NODES);
    const f32x4* A1 = (const f32x4*)(A + (size_t)(r0 + 1) * N_NODES);
    const f32x4* A2 = (const f32x4*)(A + (size_t)(r0 + 2) * N_NODES);
    const f32x4* A3 = (const f32x4*)(A + (size_t)(r0 + 3) * N_NODES);
    const f32x4* F4 = (const f32x4*)f;

#define BODY(c)                                                                     \
    {                                                                               \
        f32x4 a0, a1, a2, a3;                                                       \
        if (FIRST) {                                                                \
            a0 = A0[c]; a1 = A1[c]; a2 = A2[c]; a3 = A3[c];                         \
        } else {                                                                    \
            a0 = __builtin_nontemporal_load(A0 + (c));                              \
            a1 = __builtin_nontemporal_load(A1 + (c));                              \
            a2 = __builtin_nontemporal_load(A2 + (c));                              \
            a3 = __builtin_nontemporal_load(A3 + (c));                              \
        }                                                                           \
        f32x4 f4;                                                                   \
        if (FIRST) f4 = F4[c];                                                      \
        _Pragma("unroll")                                                           \
        for (int j = 0; j < EMB; ++j) {                                             \
            f32x4 e;                                                               \
            if (FIRST) {                                                            \
                e.x = fmaxf(f4.x * wsw[j] + cb2[j], 0.f);                           \
                e.y = fmaxf(f4.y * wsw[j] + cb2[j], 0.f);                           \
                e.z = fmaxf(f4.z * wsw[j] + cb2[j], 0.f);                           \
                e.w = fmaxf(f4.w * wsw[j] + cb2[j], 0.f);                           \
            } else {                                                                \
                e = ((const f32x4*)(embT_in + (size_t)j * N_NODES))[c];             \
            }                                                                       \
            acc[0][j] += a0.x * e.x + a0.y * e.y + a0.z * e.z + a0.w * e.w;         \
            acc[1][j] += a1.x * e.x + a1.y * e.y + a1.z * e.z + a1.w * e.w;         \
            acc[2][j] += a2.x * e.x + a2.y * e.y + a2.z * e.z + a2.w * e.w;         \
            acc[3][j] += a3.x * e.x + a3.y * e.y + a3.z * e.z + a3.w * e.w;         \
        }                                                                           \
    }

    // 2500 chunks = 9 full 256-chunk steps + 196-chunk tail
#pragma unroll 1
    for (int s = 0; s < 9; ++s) { int c = s * 256 + tid; BODY(c) }
    if (tid < NCHUNK - 9 * 256) { int c = 9 * 256 + tid; BODY(c) }
#undef BODY

    // 64-lane butterfly: every lane ends with the wave's full partials
#pragma unroll
    for (int m = 1; m < 64; m <<= 1)
#pragma unroll
        for (int r = 0; r < ROWS; ++r)
#pragma unroll
            for (int j = 0; j < EMB; ++j) acc[r][j] += __shfl_xor(acc[r][j], m, 64);

    // cross-wave combine via LDS
    __shared__ float part[4][ROWS * EMB];
    __shared__ float colp[ROWS * EMB];
    if (lane == 0)
#pragma unroll
        for (int r = 0; r < ROWS; ++r)
#pragma unroll
            for (int j = 0; j < EMB; ++j) part[wave][r * EMB + j] = acc[r][j];
    __syncthreads();

    if (tid < ROWS * EMB) {
        int r = tid / EMB, j = tid % EMB;
        float v = wnp_b[j];
        v = 0.f;
#pragma unroll
        for (int k = 0; k < EMB; ++k) {
            float yk = part[0][r * EMB + k] + part[1][r * EMB + k] +
                       part[2][r * EMB + k] + part[3][r * EMB + k];
            v += yk * wnp_w[k * EMB + j];
        }
        int i = r0 + r;
        v = fmaxf(f[i] * wsw[j] + cb2[j] + v, 0.f);
        if (FIRST) {
            embT_out[(size_t)j * N_NODES + i] = v;   // pass 2 only needs transposed
        } else {
            emb_out[(size_t)i * EMB + j] = v;        // final embeddings -> output buffer
            colp[tid] = v;
        }
    }
    if (!FIRST) {
        __syncthreads();
        if (tid < EMB)   // one atomic per column per block (k_colsum folded in)
            atomicAdd(&ssum[tid],
                      colp[tid] + colp[EMB + tid] + colp[2 * EMB + tid] + colp[3 * EMB + tid]);
    }
}

// ---- K4: q_vals; trailing linears (k_prep2) folded in, computed per block ----
__global__ void k_out(const float* __restrict__ embRM, const float* __restrict__ ssum,
                      const float* __restrict__ wqa_w, const float* __restrict__ wqa_b,
                      const float* __restrict__ wqr_w, const float* __restrict__ wqr_b,
                      const float* __restrict__ wqact_w, const float* __restrict__ wqact_b,
                      float* __restrict__ q_out) {
    __shared__ float s_qvec[EMB];
    __shared__ float s_qc;
    int t = threadIdx.x;
    if (t == 0) {
        float qc = wqr_b[0];
        for (int tt = 0; tt < EMB; ++tt) {
            float se = wqa_b[tt];
            for (int k = 0; k < EMB; ++k) se += ssum[k] * wqa_w[k * EMB + tt];
            qc += se * wqr_w[tt] + wqact_b[tt] * wqr_w[EMB + tt];
        }
        s_qc = qc;
    }
    if (t < EMB) {
        float qv = 0.f;
#pragma unroll
        for (int j = 0; j < EMB; ++j) qv += wqact_w[t * EMB + j] * wqr_w[EMB + j];
        s_qvec[t] = qv;
    }
    __syncthreads();
    int i = blockIdx.x * blockDim.x + t;
    if (i < N_NODES) {
        float q = s_qc;
#pragma unroll
        for (int j = 0; j < EMB; ++j) q += embRM[(size_t)i * EMB + j] * s_qvec[j];
        q_out[i] = q;
    }
}

extern "C" void kernel_launch(void* const* d_in, const int* in_sizes, int n_in,
                              void* d_out, int out_size, void* d_ws, size_t ws_size,
                              hipStream_t stream) {
    (void)n_in; (void)out_size; (void)ws_size;
    const float* f      = (const float*)d_in[0];
    const float* w      = (const float*)d_in[1];
    const float* A      = (const float*)d_in[2];
    const float* ws_w   = (const float*)d_in[3];
    const float* ws_b   = (const float*)d_in[4];
    const float* wnp_w  = (const float*)d_in[5];
    const float* wnp_b  = (const float*)d_in[6];
    const float* wnw_w  = (const float*)d_in[7];
    const float* wnw_b  = (const float*)d_in[8];
    const float* wew_w  = (const float*)d_in[9];
    const float* wew_b  = (const float*)d_in[10];
    const float* wqr_w  = (const float*)d_in[11];
    const float* wqr_b  = (const float*)d_in[12];
    const float* wqa_w  = (const float*)d_in[13];
    const float* wqa_b  = (const float*)d_in[14];
    const float* wqact_w = (const float*)d_in[15];
    const float* wqact_b = (const float*)d_in[16];
    float* ws  = (float*)d_ws;
    float* out = (float*)d_out;
    const int E = in_sizes[1];

    float* outEmb = out + N_NODES;   // embeddings written directly into output

    hipMemsetAsync(ws, 0, 64 * sizeof(float), stream);
    k_edge_sum<<<256, 256, 0, stream>>>(w, E, wew_w, wew_b, ws + WS_SEDGE);
    // pass 1 (math iters 1+2 fused): e on the fly from f
    k_iter<true><<<N_NODES / ROWS, 256, 0, stream>>>(
        A, nullptr, f, ws_w, ws_b, wnp_w, wnp_b, wnw_w, wnw_b, ws + WS_SEDGE,
        ws + WS_EMBT, nullptr, nullptr);
    // pass 2 (math iter 3): reads embT; colsum fused via per-block atomics
    k_iter<false><<<N_NODES / ROWS, 256, 0, stream>>>(
        A, ws + WS_EMBT, f, ws_w, ws_b, wnp_w, wnp_b, wnw_w, wnw_b, ws + WS_SEDGE,
        nullptr, outEmb, ws + WS_SSUM);
    k_out<<<(N_NODES + 255) / 256, 256, 0, stream>>>(outEmb, ws + WS_SSUM,
                                                     wqa_w, wqa_b, wqr_w, wqr_b,
                                                     wqact_w, wqact_b, out);
}